// Round 7
// baseline (11307.310 us; speedup 1.0000x reference)
//
#include <hip/hip_runtime.h>
#include <hip/hip_bf16.h>
#include <cstddef>

#define BB 64
#define TXX 128
#define TYY 48
#define NSS 47
#define EE 512
#define HH 1024
#define VV 32000

typedef _Float16 f16x8 __attribute__((ext_vector_type(8)));
typedef float f32x4 __attribute__((ext_vector_type(4)));
typedef unsigned short ush;
typedef ush ushx4 __attribute__((ext_vector_type(4)));

__device__ __forceinline__ ush f2h(float x) {
    _Float16 h = (_Float16)x;
    return __builtin_bit_cast(ush, h);
}
__device__ __forceinline__ float h2f(ush u) {
    return (float)__builtin_bit_cast(_Float16, u);
}
// cached global->LDS DMA (weights only; plain aux=0 — proven rounds 1-4)
__device__ __forceinline__ void gload16(const void* g, void* l) {
    __builtin_amdgcn_global_load_lds(
        (const __attribute__((address_space(1))) unsigned int*)g,
        (__attribute__((address_space(3))) unsigned int*)l, 16, 0, 0);
}
__device__ __forceinline__ void st_agent_u32(void* p, unsigned v) {
    __hip_atomic_store((unsigned*)p, v, __ATOMIC_RELAXED, __HIP_MEMORY_SCOPE_AGENT);
}
__device__ __forceinline__ unsigned ld_agent_u32(const void* p) {
    return __hip_atomic_load((const unsigned*)p, __ATOMIC_RELAXED, __HIP_MEMORY_SCOPE_AGENT);
}
__device__ __forceinline__ float sigm(float x) { return 1.f / (1.f + expf(-x)); }

// Relaxed grid barrier: no cache maintenance. All cross-block data moves via
// agent-scope (L3-coherent) ops; vmcnt(0) orders them before the arrive.
__device__ __forceinline__ void gbar(unsigned* bar, unsigned target) {
    asm volatile("s_waitcnt vmcnt(0)" ::: "memory");
    __syncthreads();
    if (threadIdx.x == 0) {
        __hip_atomic_fetch_add(bar, 1u, __ATOMIC_RELAXED, __HIP_MEMORY_SCOPE_AGENT);
        while (__hip_atomic_load(bar, __ATOMIC_RELAXED, __HIP_MEMORY_SCOPE_AGENT) < target) {
            __builtin_amdgcn_s_sleep(2);
        }
    }
    __syncthreads();
}

// ---------------------------------------------------------------------------
// Transpose + f32->f16 (unchanged)
// ---------------------------------------------------------------------------
__global__ __launch_bounds__(256) void transpose_w(
    const float* __restrict__ W, ush* __restrict__ Wt, int ldW, int ldT)
{
    __shared__ float t[32][33];
    int v0 = blockIdx.x * 32, k0 = blockIdx.y * 32;
    int tv = threadIdx.x & 31, tk = threadIdx.x >> 5;
    #pragma unroll
    for (int i = 0; i < 4; i++) {
        int k = tk * 4 + i;
        t[k][tv] = W[(size_t)(k0 + k) * ldW + v0 + tv];
    }
    __syncthreads();
    #pragma unroll
    for (int i = 0; i < 4; i++) {
        int v = tk * 4 + i;
        Wt[(size_t)(v0 + v) * ldT + k0 + tv] = f2h(t[tv][v]);
    }
}

// ---------------------------------------------------------------------------
// Embedding gather + f16 convert (unchanged)
// ---------------------------------------------------------------------------
__global__ __launch_bounds__(256) void gather_emb(
    const float* __restrict__ emb, const int* __restrict__ tok,
    ush* __restrict__ out, int tokld, int tmax)
{
    int i = blockIdx.x * 256 + threadIdx.x;
    int r = i >> 6, kq = (i & 63) * 8;
    int t = r >> 6, b = r & 63;
    ush v[8];
    if (t < tmax) {
        int tk = tok[b * tokld + t];
        const float* e = emb + (size_t)tk * EE + kq;
        #pragma unroll
        for (int j = 0; j < 8; j++) v[j] = f2h(e[j]);
    } else {
        #pragma unroll
        for (int j = 0; j < 8; j++) v[j] = 0;
    }
    *reinterpret_cast<f16x8*>(&out[(size_t)r * EE + kq]) =
        *reinterpret_cast<f16x8*>(v);
}

// ---------------------------------------------------------------------------
// f16 MFMA GEMM, 128x128 tile (unchanged; proven). MODE 1: out-proj permute,
// MODE 2: f16 C row-major.
// ---------------------------------------------------------------------------
template <int MODE>
__global__ __launch_bounds__(256) void gemm_f16(
    const ush* __restrict__ A, int lda, const ush* __restrict__ Bt,
    const float* __restrict__ bias, void* __restrict__ Cv,
    int K, int Nld, int Mvalid)
{
    __shared__ ush As[128 * 64];
    __shared__ ush Bs[128 * 64];
    const int tid = threadIdx.x;
    const int lane = tid & 63;
    const int w = tid >> 6;
    const int wm = w >> 1, wn = w & 1;
    const int m0 = blockIdx.x * 128;
    const int n0 = blockIdx.y * 128;

    f32x4 acc[4][4] = {};
    const int srow = w * 32 + (lane >> 3);
    const int skoff = (lane & 7) * 8;

    for (int kb = 0; kb < K; kb += 64) {
        #pragma unroll
        for (int c = 0; c < 4; c++) {
            const ush* ga = A + (size_t)(m0 + srow + c * 8) * lda + kb + skoff;
            gload16(ga, &As[(w * 4 + c) * 512]);
        }
        #pragma unroll
        for (int c = 0; c < 4; c++) {
            const ush* gb = Bt + (size_t)(n0 + srow + c * 8) * K + kb + skoff;
            gload16(gb, &Bs[(w * 4 + c) * 512]);
        }
        __syncthreads();

        #pragma unroll
        for (int kw = 0; kw < 2; kw++) {
            const int koff = kw * 32 + (lane >> 4) * 8;
            f16x8 af[4], bf[4];
            #pragma unroll
            for (int m = 0; m < 4; m++)
                af[m] = *(const f16x8*)&As[(wm * 64 + m * 16 + (lane & 15)) * 64 + koff];
            #pragma unroll
            for (int n = 0; n < 4; n++)
                bf[n] = *(const f16x8*)&Bs[(wn * 64 + n * 16 + (lane & 15)) * 64 + koff];
            #pragma unroll
            for (int m = 0; m < 4; m++)
                #pragma unroll
                for (int n = 0; n < 4; n++)
                    acc[m][n] = __builtin_amdgcn_mfma_f32_16x16x32_f16(
                        af[m], bf[n], acc[m][n], 0, 0, 0);
        }
        __syncthreads();
    }

    #pragma unroll
    for (int n = 0; n < 4; n++) {
        int v = n0 + wn * 64 + n * 16 + (lane & 15);
        float bs = (MODE == 1) ? bias[v] : 0.f;
        #pragma unroll
        for (int m = 0; m < 4; m++) {
            int rbase = m0 + wm * 64 + m * 16 + (lane >> 4) * 4;
            #pragma unroll
            for (int r = 0; r < 4; r++) {
                int row = rbase + r;
                float val = acc[m][n][r] + bs;
                if (MODE == 1) {
                    if (row < 3008) {
                        int b = row & 63, s = row >> 6;
                        ((float*)Cv)[((size_t)b * NSS + s) * VV + v] = val;
                    }
                } else {
                    if (row < Mvalid) ((ush*)Cv)[(size_t)row * Nld + v] = f2h(val);
                }
            }
        }
    }
}

// ===========================================================================
// Persistent recurrent kernel: 64 blocks x 256 threads, relaxed grid barrier.
// PLAIN launch (not cooperative): 64 blocks co-reside trivially on 256 CUs.
// A-tiles (recurrent state) staged via agent-coherent dword loads -> regs ->
// ds_write_b128. Weights staged via plain cached global_load_lds.
// One __syncthreads per K-chunk; As[2]/Ws[3] rotation.
// ===========================================================================
struct RecArgs {
    ush *comb0, *comb1;
    float* c;
    const ush *Whe, *Whd, *Gxe, *Gxd;
    const float *ebi, *ebf, *ebo, *ebc;
    const float *dbi, *dbf, *dbo, *dbc;
    const ush *attn_t, *lin_t;
    const float *attn_b, *lin_b;
    float* q;
    ush *enc16, *preh;
    unsigned* bar;
};

// A-chunk: 64 rows x 128 cols f16 = 16 KB; thread owns 4 x 16B slots.
__device__ __forceinline__ void loadA(const ush* __restrict__ base, int kb,
                                      int w, int lane, uint4 ra[4])
{
    #pragma unroll
    for (int c8 = 0; c8 < 4; c8++) {
        int s = (c8 * 4 + w) * 64 + lane;
        int r = s >> 4, scc = (s & 15) ^ (r & 7);
        const unsigned* p = (const unsigned*)(base + (size_t)r * 2048 + kb + scc * 8);
        ra[c8].x = ld_agent_u32(p);
        ra[c8].y = ld_agent_u32(p + 1);
        ra[c8].z = ld_agent_u32(p + 2);
        ra[c8].w = ld_agent_u32(p + 3);
    }
}
__device__ __forceinline__ void writeA(ush* As, int w, int lane, const uint4 ra[4])
{
    #pragma unroll
    for (int c8 = 0; c8 < 4; c8++) {
        int s = (c8 * 4 + w) * 64 + lane;
        *reinterpret_cast<uint4*>(&As[s * 8]) = ra[c8];
    }
}
// Wh chunk: 64 weight-rows (4 gates x 16 cols of block j) x 128 k
__device__ __forceinline__ void stageWh(const ush* __restrict__ Wh, int j, int kb,
                                        int w, int lane, ush* Ws)
{
    #pragma unroll
    for (int c8 = 0; c8 < 4; c8++) {
        int s = (c8 * 4 + w) * 64 + lane;
        int r = s >> 4, scc = (s & 15) ^ (r & 7);
        gload16(Wh + ((size_t)((r >> 4) * 1024 + j * 16 + (r & 15))) * 1024 + kb + scc * 8,
                Ws + (size_t)(c8 * 4 + w) * 512);
    }
}
// 16-row weight chunk (q / lin): 16 rows x 128 k = 4 KB
__device__ __forceinline__ void stageWq(const ush* __restrict__ Wq, int j, int ldq,
                                        int kb, int w, int lane, ush* Ws)
{
    int s = w * 64 + lane;
    int r = s >> 4, scc = (s & 15) ^ (r & 7);
    gload16(Wq + (size_t)(j * 16 + r) * ldq + kb + scc * 8, Ws + (size_t)w * 512);
}

__device__ __forceinline__ void compute4(int w, int lane, const ush* As,
                                         const ush* Ws, f32x4 acc[4])
{
    #pragma unroll
    for (int kw = 0; kw < 4; kw++) {
        int colo = kw * 32 + (lane >> 4) * 8;
        int ar = w * 16 + (lane & 15);
        f16x8 af = *(const f16x8*)&As[(ar * 128 + colo) ^ ((ar & 7) << 3)];
        #pragma unroll
        for (int g = 0; g < 4; g++) {
            int br = g * 16 + (lane & 15);
            f16x8 bfv = *(const f16x8*)&Ws[(br * 128 + colo) ^ ((br & 7) << 3)];
            acc[g] = __builtin_amdgcn_mfma_f32_16x16x32_f16(af, bfv, acc[g], 0, 0, 0);
        }
    }
}
__device__ __forceinline__ void compute1(int w, int lane, const ush* As,
                                         const ush* Ws, f32x4& acc)
{
    #pragma unroll
    for (int kw = 0; kw < 4; kw++) {
        int colo = kw * 32 + (lane >> 4) * 8;
        int ar = w * 16 + (lane & 15);
        f16x8 af = *(const f16x8*)&As[(ar * 128 + colo) ^ ((ar & 7) << 3)];
        int br = lane & 15;
        f16x8 bfv = *(const f16x8*)&Ws[(br * 128 + colo) ^ ((br & 7) << 3)];
        acc = __builtin_amdgcn_mfma_f32_16x16x32_f16(af, bfv, acc, 0, 0, 0);
    }
}

template <int ISENC>
__device__ __forceinline__ void phase_step(
    int j, int w, int lane, ush As[2][8192], ush Ws[3][8192],
    const ush* __restrict__ hsrc, ush* __restrict__ hdst,
    const ush* __restrict__ Wh, const ush* __restrict__ Gx,
    const float* __restrict__ bi, const float* __restrict__ bfg,
    const float* __restrict__ bo, const float* __restrict__ bc,
    float* __restrict__ c, ush* __restrict__ enc_slot)
{
    f32x4 acc[4] = {};
    uint4 ra[4];
    __syncthreads();                       // previous phase done with LDS
    loadA(hsrc, 0, w, lane, ra);
    writeA(As[0], w, lane, ra);
    loadA(hsrc, 128, w, lane, ra);
    stageWh(Wh, j, 0, w, lane, Ws[0]);
    stageWh(Wh, j, 128, w, lane, Ws[1]);
    for (int k = 0; k < 8; k++) {
        __syncthreads();                   // drains DMA + ds_writes; buffers ready
        if (k + 1 < 8) writeA(As[(k + 1) & 1], w, lane, ra);
        if (k + 2 < 8) {
            loadA(hsrc, (k + 2) * 128, w, lane, ra);
            stageWh(Wh, j, (k + 2) * 128, w, lane, Ws[(k + 2) % 3]);
        }
        compute4(w, lane, As[k & 1], Ws[k % 3], acc);
    }

    const int cc = j * 16 + (lane & 15);
    const float Bi = bi[cc], Bf = bfg[cc], Bo = bo[cc], Bc = bc[cc];
    #pragma unroll
    for (int r = 0; r < 4; r++) {
        int row = w * 16 + (lane >> 4) * 4 + r;
        const ush* gx = Gx + (size_t)row * 4096;
        float zi = acc[0][r] + Bi + h2f(gx[cc]);
        float zf = acc[1][r] + Bf + h2f(gx[1024 + cc]);
        float zo = acc[2][r] + Bo + h2f(gx[2048 + cc]);
        float zc = acc[3][r] + Bc + h2f(gx[3072 + cc]);
        float F = sigm(zf), I = sigm(zi), O = sigm(zo), G = tanhf(zc);
        size_t ci = (size_t)row * 1024 + cc;
        float cn = F * c[ci] + I * G;
        c[ci] = cn;
        float hn = O * tanhf(cn);
        unsigned hv = (unsigned)f2h(hn);
        unsigned other = __shfl_xor(hv, 1, 64);
        if ((lane & 1) == 0) {
            unsigned packed = hv | (other << 16);
            st_agent_u32(&hdst[(size_t)row * 2048 + cc], packed);
            if (ISENC) st_agent_u32(&enc_slot[ci], packed);
        }
    }
}

// generic 16-col GEMM phase body (q: K=1024, lin: K=2048)
template <int NCH>
__device__ __forceinline__ f32x4 narrow_gemm(
    int j, int w, int lane, ush As[2][8192], ush Ws[3][8192],
    const ush* __restrict__ hsrc, const ush* __restrict__ Wq, int ldq)
{
    f32x4 acc = {};
    uint4 ra[4];
    __syncthreads();
    loadA(hsrc, 0, w, lane, ra);
    writeA(As[0], w, lane, ra);
    loadA(hsrc, 128, w, lane, ra);
    stageWq(Wq, j, ldq, 0, w, lane, Ws[0]);
    stageWq(Wq, j, ldq, 128, w, lane, Ws[1]);
    for (int k = 0; k < NCH; k++) {
        __syncthreads();
        if (k + 1 < NCH) writeA(As[(k + 1) & 1], w, lane, ra);
        if (k + 2 < NCH) {
            loadA(hsrc, (k + 2) * 128, w, lane, ra);
            stageWq(Wq, j, ldq, (k + 2) * 128, w, lane, Ws[(k + 2) % 3]);
        }
        compute1(w, lane, As[k & 1], Ws[k % 3], acc);
    }
    return acc;
}

__device__ __forceinline__ void phase_attn(
    int b, int tid, ush* As0, ush* Ws0,
    const float* __restrict__ qbuf, const ush* __restrict__ enc16,
    ush* __restrict__ ctxdst)
{
    float* qs = (float*)As0;
    float* sc = (float*)Ws0;

    for (int i = tid; i < 1024; i += 256)
        qs[i] = __builtin_bit_cast(float, ld_agent_u32(&qbuf[(size_t)b * 1024 + i]));
    __syncthreads();

    int wave = tid >> 6, lane = tid & 63;
    for (int i = 0; i < 32; i++) {
        int t = wave * 32 + i;
        const ush* e = enc16 + ((size_t)t * 64 + b) * 1024;
        float s = 0.f;
        #pragma unroll
        for (int jj = 0; jj < 16; jj++) s += qs[lane + jj * 64] * h2f(e[lane + jj * 64]);
        #pragma unroll
        for (int o = 32; o > 0; o >>= 1) s += __shfl_down(s, o, 64);
        if (lane == 0) sc[t] = s;
    }
    __syncthreads();

    if (wave == 0) {
        float v = fmaxf(sc[lane], sc[lane + 64]);
        #pragma unroll
        for (int o = 32; o > 0; o >>= 1) v = fmaxf(v, __shfl_down(v, o, 64));
        if (lane == 0) sc[128] = v;
    }
    __syncthreads();
    float mx = sc[128];
    if (wave == 0) {
        float e0 = expf(sc[lane] - mx), e1 = expf(sc[lane + 64] - mx);
        sc[lane] = e0; sc[lane + 64] = e1;
        float v = e0 + e1;
        #pragma unroll
        for (int o = 32; o > 0; o >>= 1) v += __shfl_down(v, o, 64);
        if (lane == 0) sc[129] = v;
    }
    __syncthreads();
    float inv = 1.f / sc[129];

    int h0 = tid * 4;
    float a0 = 0.f, a1 = 0.f, a2 = 0.f, a3 = 0.f;
    #pragma unroll 4
    for (int t = 0; t < 128; t++) {
        float a = sc[t] * inv;
        ushx4 ev = *reinterpret_cast<const ushx4*>(
            enc16 + ((size_t)t * 64 + b) * 1024 + h0);
        a0 += a * h2f(ev[0]); a1 += a * h2f(ev[1]);
        a2 += a * h2f(ev[2]); a3 += a * h2f(ev[3]);
    }
    unsigned p0 = (unsigned)f2h(a0) | ((unsigned)f2h(a1) << 16);
    unsigned p1 = (unsigned)f2h(a2) | ((unsigned)f2h(a3) << 16);
    st_agent_u32(&ctxdst[(size_t)b * 2048 + h0], p0);
    st_agent_u32(&ctxdst[(size_t)b * 2048 + h0 + 2], p1);
    __syncthreads();
}

__global__ __launch_bounds__(256) void recurrent_all(RecArgs a)
{
    __shared__ ush As[2][8192];   // 32 KB
    __shared__ ush Ws[3][8192];   // 48 KB
    const int j = blockIdx.x;
    const int tid = threadIdx.x;
    const int w = tid >> 6, lane = tid & 63;
    ush* comb[2] = {a.comb0, a.comb1};
    unsigned nb = 0;

    for (int t = 0; t < TXX; t++) {
        phase_step<1>(j, w, lane, As, Ws, comb[t & 1], comb[(t + 1) & 1], a.Whe,
                      a.Gxe + (size_t)t * 64 * 4096, a.ebi, a.ebf, a.ebo, a.ebc,
                      a.c, a.enc16 + (size_t)t * 65536);
        nb++; gbar(a.bar, nb * 64u);
    }

    int cur = 0;
    for (int s = 0; s < NSS; s++) {
        int nxt = cur ^ 1;
        phase_step<0>(j, w, lane, As, Ws, comb[cur], comb[nxt], a.Whd,
                      a.Gxd + (size_t)s * 64 * 4096, a.dbi, a.dbf, a.dbo, a.dbc,
                      a.c, nullptr);
        nb++; gbar(a.bar, nb * 64u);
        {
            f32x4 acc = narrow_gemm<8>(j, w, lane, As, Ws, comb[nxt], a.attn_t, 1024);
            int col = j * 16 + (lane & 15);
            float bsv = a.attn_b[col];
            #pragma unroll
            for (int r = 0; r < 4; r++) {
                int row = w * 16 + (lane >> 4) * 4 + r;
                st_agent_u32(&a.q[(size_t)row * 1024 + col],
                             __builtin_bit_cast(unsigned, acc[r] + bsv));
            }
        }
        nb++; gbar(a.bar, nb * 64u);
        phase_attn(j, tid, As[0], Ws[0], a.q, a.enc16, comb[nxt] + 1024);
        nb++; gbar(a.bar, nb * 64u);
        {
            f32x4 acc = narrow_gemm<16>(j, w, lane, As, Ws, comb[nxt], a.lin_t, 2048);
            int col = j * 16 + (lane & 15);
            float bsv = a.lin_b[col];
            #pragma unroll
            for (int r = 0; r < 4; r++) {
                int row = w * 16 + (lane >> 4) * 4 + r;
                a.preh[((size_t)(s * 64 + row)) * 1024 + col] = f2h(tanhf(acc[r] + bsv));
            }
        }
        // no grid barrier: next phase_step reads only comb[nxt] h (read-read)
        cur = nxt;
    }
}

// ---------------------------------------------------------------------------
extern "C" void kernel_launch(void* const* d_in, const int* in_sizes, int n_in,
                              void* d_out, int out_size, void* d_ws, size_t ws_size,
                              hipStream_t stream)
{
    const int*   x       = (const int*)d_in[0];
    const int*   y       = (const int*)d_in[1];
    const float* enc_emb = (const float*)d_in[2];
    const float* dec_emb = (const float*)d_in[3];
    const float* encW[4] = {(const float*)d_in[4], (const float*)d_in[6],
                            (const float*)d_in[8], (const float*)d_in[10]};
    const float* encB[4] = {(const float*)d_in[5], (const float*)d_in[7],
                            (const float*)d_in[9], (const float*)d_in[11]};
    const float* decW[4] = {(const float*)d_in[12], (const float*)d_in[14],
                            (const float*)d_in[16], (const float*)d_in[18]};
    const float* decB[4] = {(const float*)d_in[13], (const float*)d_in[15],
                            (const float*)d_in[17], (const float*)d_in[19]};
    const float* attn_w  = (const float*)d_in[20];
    const float* attn_b  = (const float*)d_in[21];
    const float* lin_w   = (const float*)d_in[22];
    const float* lin_b   = (const float*)d_in[23];
    const float* out_w   = (const float*)d_in[24];
    const float* out_b   = (const float*)d_in[25];

    float* ws = (float*)d_ws;
    float* c      = ws;                          // 65536 f
    ush*   comb0  = (ush*)(ws + 65536);          // 131072 f
    ush*   comb1  = (ush*)(ws + 196608);         // 131072 f
    float* q      = ws + 327680;                 // 65536 f
    ush*   preh   = (ush*)(ws + 393216);         // 1572864 f (3072 rows; 3008 valid)
    ush*   enc16  = (ush*)(ws + 1966080);        // 4194304 f
    ush*   Wt     = (ush*)(ws + 6160384);        // 16384000 f
    ush*   Whe    = (ush*)(ws + 22544384);       // 2097152 f
    ush*   Whd    = (ush*)(ws + 24641536);       // 2097152 f
    ush*   Wxe    = (ush*)(ws + 26738688);       // 1048576 f
    ush*   Wxd    = (ush*)(ws + 27787264);       // 1048576 f
    ush*   attn_t = (ush*)(ws + 28835840);       // 524288 f
    ush*   lin_t  = (ush*)(ws + 29360128);       // 1048576 f (end 30408704 f)
    // barrier counter lives in preh's PAD rows (3008..3071): zeroed by the
    // preh memset each launch, never written by lin, only read as discarded
    // A-padding by the guarded out-proj epilogue (finite small values).
    unsigned* bar = (unsigned*)(preh + (size_t)3008 * 1024);

    // dead-before-outproj scratch in d_out
    ush* Gx_enc = (ush*)d_out;                   // 8192*4096
    ush* Gx_dec = Gx_enc + (size_t)8192 * 4096;  // 3072*4096
    ush* Xe     = Gx_dec + (size_t)3072 * 4096;  // 8192*512
    ush* Ye     = Xe + (size_t)8192 * 512;       // 3072*512

    hipMemsetAsync(c, 0, (size_t)327680 * 4, stream);        // c + comb0 + comb1
    hipMemsetAsync(preh, 0, (size_t)3072 * 1024 * 2, stream); // incl. pad + bar

    // ---- weight prep ----
    transpose_w<<<dim3(VV / 32, 32), 256, 0, stream>>>(out_w, Wt, VV, HH);
    transpose_w<<<dim3(32, 32), 256, 0, stream>>>(attn_w, attn_t, HH, HH);
    transpose_w<<<dim3(32, 64), 256, 0, stream>>>(lin_w, lin_t, HH, 2048);
    for (int g = 0; g < 4; g++) {
        transpose_w<<<dim3(32, 32), 256, 0, stream>>>(
            encW[g] + (size_t)EE * HH, Whe + (size_t)g * 1024 * 1024, HH, HH);
        transpose_w<<<dim3(32, 32), 256, 0, stream>>>(
            decW[g] + (size_t)EE * HH, Whd + (size_t)g * 1024 * 1024, HH, HH);
        transpose_w<<<dim3(32, 16), 256, 0, stream>>>(
            encW[g], Wxe + (size_t)g * 1024 * 512, HH, EE);
        transpose_w<<<dim3(32, 16), 256, 0, stream>>>(
            decW[g], Wxd + (size_t)g * 1024 * 512, HH, EE);
    }

    // ---- embedding gathers ----
    gather_emb<<<dim3(2048), 256, 0, stream>>>(enc_emb, x, Xe, TXX, TXX);
    gather_emb<<<dim3(768), 256, 0, stream>>>(dec_emb, y, Ye, TYY, NSS);

    // ---- x-side gate precompute ----
    gemm_f16<2><<<dim3(64, 32), 256, 0, stream>>>(
        Xe, EE, Wxe, nullptr, Gx_enc, EE, 4096, 8192);
    gemm_f16<2><<<dim3(24, 32), 256, 0, stream>>>(
        Ye, EE, Wxd, nullptr, Gx_dec, EE, 4096, 3072);

    // ---- persistent recurrent kernel (PLAIN launch; 64 blocks co-reside) ----
    RecArgs ra;
    ra.comb0 = comb0; ra.comb1 = comb1; ra.c = c;
    ra.Whe = Whe; ra.Whd = Whd; ra.Gxe = Gx_enc; ra.Gxd = Gx_dec;
    ra.ebi = encB[0]; ra.ebf = encB[1]; ra.ebo = encB[2]; ra.ebc = encB[3];
    ra.dbi = decB[0]; ra.dbf = decB[1]; ra.dbo = decB[2]; ra.dbc = decB[3];
    ra.attn_t = attn_t; ra.lin_t = lin_t; ra.attn_b = attn_b; ra.lin_b = lin_b;
    ra.q = q; ra.enc16 = enc16; ra.preh = preh; ra.bar = bar;
    recurrent_all<<<dim3(64), dim3(256), 0, stream>>>(ra);

    // ---- output projection ----
    gemm_f16<1><<<dim3(24, VV / 128), 256, 0, stream>>>(
        preh, HH, Wt, out_b, d_out, HH, VV, 3008);
}

// Round 8
// 5157.011 us; speedup vs baseline: 2.1926x; 2.1926x over previous
//
#include <hip/hip_runtime.h>
#include <hip/hip_bf16.h>
#include <hip/hip_cooperative_groups.h>
#include <cstddef>

namespace cg = cooperative_groups;

#define BB 64
#define TXX 128
#define TYY 48
#define NSS 47
#define EE 512
#define HH 1024
#define VV 32000

typedef _Float16 f16x8 __attribute__((ext_vector_type(8)));
typedef float f32x4 __attribute__((ext_vector_type(4)));
typedef unsigned short ush;
typedef ush ushx4 __attribute__((ext_vector_type(4)));

__device__ __forceinline__ ush f2h(float x) {
    _Float16 h = (_Float16)x;
    return __builtin_bit_cast(ush, h);
}
__device__ __forceinline__ float h2f(ush u) {
    return (float)__builtin_bit_cast(_Float16, u);
}
// cached global->LDS DMA (proven rounds 1-4)
__device__ __forceinline__ void gload16(const void* g, void* l) {
    __builtin_amdgcn_global_load_lds(
        (const __attribute__((address_space(1))) unsigned int*)g,
        (__attribute__((address_space(3))) unsigned int*)l, 16, 0, 0);
}
__device__ __forceinline__ float sigm(float x) { return 1.f / (1.f + expf(-x)); }

// ---------------------------------------------------------------------------
// Transpose + f32->f16 (unchanged)
// ---------------------------------------------------------------------------
__global__ __launch_bounds__(256) void transpose_w(
    const float* __restrict__ W, ush* __restrict__ Wt, int ldW, int ldT)
{
    __shared__ float t[32][33];
    int v0 = blockIdx.x * 32, k0 = blockIdx.y * 32;
    int tv = threadIdx.x & 31, tk = threadIdx.x >> 5;
    #pragma unroll
    for (int i = 0; i < 4; i++) {
        int k = tk * 4 + i;
        t[k][tv] = W[(size_t)(k0 + k) * ldW + v0 + tv];
    }
    __syncthreads();
    #pragma unroll
    for (int i = 0; i < 4; i++) {
        int v = tk * 4 + i;
        Wt[(size_t)(v0 + v) * ldT + k0 + tv] = f2h(t[tv][v]);
    }
}

// ---------------------------------------------------------------------------
// Embedding gather + f16 convert (unchanged)
// ---------------------------------------------------------------------------
__global__ __launch_bounds__(256) void gather_emb(
    const float* __restrict__ emb, const int* __restrict__ tok,
    ush* __restrict__ out, int tokld, int tmax)
{
    int i = blockIdx.x * 256 + threadIdx.x;
    int r = i >> 6, kq = (i & 63) * 8;
    int t = r >> 6, b = r & 63;
    ush v[8];
    if (t < tmax) {
        int tk = tok[b * tokld + t];
        const float* e = emb + (size_t)tk * EE + kq;
        #pragma unroll
        for (int j = 0; j < 8; j++) v[j] = f2h(e[j]);
    } else {
        #pragma unroll
        for (int j = 0; j < 8; j++) v[j] = 0;
    }
    *reinterpret_cast<f16x8*>(&out[(size_t)r * EE + kq]) =
        *reinterpret_cast<f16x8*>(v);
}

// ---------------------------------------------------------------------------
// f16 MFMA GEMM, 128x128 tile (proven). MODE:
//  0: f32 C row-major [row*Nld+v] + bias, guard row<Mvalid
//  1: out-projection permute + bias, guard row<3008
//  2: f16 C row-major, guard row<Mvalid
//  3: f16 C row-major, tanh(acc+bias), guard row<Mvalid
// ---------------------------------------------------------------------------
template <int MODE>
__global__ __launch_bounds__(256) void gemm_f16(
    const ush* __restrict__ A, int lda, const ush* __restrict__ Bt,
    const float* __restrict__ bias, void* __restrict__ Cv,
    int K, int Nld, int Mvalid)
{
    __shared__ ush As[128 * 64];
    __shared__ ush Bs[128 * 64];
    const int tid = threadIdx.x;
    const int lane = tid & 63;
    const int w = tid >> 6;
    const int wm = w >> 1, wn = w & 1;
    const int m0 = blockIdx.x * 128;
    const int n0 = blockIdx.y * 128;

    f32x4 acc[4][4] = {};
    const int srow = w * 32 + (lane >> 3);
    const int skoff = (lane & 7) * 8;

    for (int kb = 0; kb < K; kb += 64) {
        #pragma unroll
        for (int c = 0; c < 4; c++) {
            const ush* ga = A + (size_t)(m0 + srow + c * 8) * lda + kb + skoff;
            gload16(ga, &As[(w * 4 + c) * 512]);
        }
        #pragma unroll
        for (int c = 0; c < 4; c++) {
            const ush* gb = Bt + (size_t)(n0 + srow + c * 8) * K + kb + skoff;
            gload16(gb, &Bs[(w * 4 + c) * 512]);
        }
        __syncthreads();

        #pragma unroll
        for (int kw = 0; kw < 2; kw++) {
            const int koff = kw * 32 + (lane >> 4) * 8;
            f16x8 af[4], bf[4];
            #pragma unroll
            for (int m = 0; m < 4; m++)
                af[m] = *(const f16x8*)&As[(wm * 64 + m * 16 + (lane & 15)) * 64 + koff];
            #pragma unroll
            for (int n = 0; n < 4; n++)
                bf[n] = *(const f16x8*)&Bs[(wn * 64 + n * 16 + (lane & 15)) * 64 + koff];
            #pragma unroll
            for (int m = 0; m < 4; m++)
                #pragma unroll
                for (int n = 0; n < 4; n++)
                    acc[m][n] = __builtin_amdgcn_mfma_f32_16x16x32_f16(
                        af[m], bf[n], acc[m][n], 0, 0, 0);
        }
        __syncthreads();
    }

    #pragma unroll
    for (int n = 0; n < 4; n++) {
        int v = n0 + wn * 64 + n * 16 + (lane & 15);
        float bs = (MODE == 2) ? 0.f : (bias ? bias[v] : 0.f);
        #pragma unroll
        for (int m = 0; m < 4; m++) {
            int rbase = m0 + wm * 64 + m * 16 + (lane >> 4) * 4;
            #pragma unroll
            for (int r = 0; r < 4; r++) {
                int row = rbase + r;
                float val = acc[m][n][r] + bs;
                if (MODE == 1) {
                    if (row < 3008) {
                        int b = row & 63, s = row >> 6;
                        ((float*)Cv)[((size_t)b * NSS + s) * VV + v] = val;
                    }
                } else if (MODE == 0) {
                    if (row < Mvalid) ((float*)Cv)[(size_t)row * Nld + v] = val;
                } else if (MODE == 2) {
                    if (row < Mvalid) ((ush*)Cv)[(size_t)row * Nld + v] = f2h(val);
                } else {  // MODE 3
                    if (row < Mvalid)
                        ((ush*)Cv)[(size_t)row * Nld + v] = f2h(tanhf(val));
                }
            }
        }
    }
}

// ===========================================================================
// Persistent recurrent kernel: ONLY the 175 LSTM steps (attention hoisted
// out — the scan carry is (h,c) only). 64 blocks x 256 threads, cooperative
// grid.sync per step. Block j owns hidden cols j*16..j*16+15 of all 4 gates.
// Wh slice (128 KB) is LDS-RESIDENT per section; A (h) reg-staged from
// plain cached uint4 loads -> ds_write, double-buffered. LDS = 160 KiB.
// ===========================================================================
struct RecArgs {
    ush *comb0, *comb1, *Hcat;
    float* c;
    const ush *Whe, *Whd, *Gxe, *Gxd;
    const float *ebi, *ebf, *ebo, *ebc;
    const float *dbi, *dbf, *dbo, *dbc;
    ush* enc16;
};

__device__ __forceinline__ void loadA(const ush* __restrict__ base, int kb,
                                      int w, int lane, uint4 ra[4])
{
    #pragma unroll
    for (int c8 = 0; c8 < 4; c8++) {
        int s = (c8 * 4 + w) * 64 + lane;
        int r = s >> 4, scc = (s & 15) ^ (r & 7);
        ra[c8] = *reinterpret_cast<const uint4*>(
            base + (size_t)r * 2048 + kb + scc * 8);
    }
}
__device__ __forceinline__ void writeA(ush* As, int w, int lane, const uint4 ra[4])
{
    #pragma unroll
    for (int c8 = 0; c8 < 4; c8++) {
        int s = (c8 * 4 + w) * 64 + lane;
        *reinterpret_cast<uint4*>(&As[s * 8]) = ra[c8];
    }
}
// Wh chunk ch (128 k): 64 weight-rows (4 gates x 16 cols of block j)
__device__ __forceinline__ void stageWh(const ush* __restrict__ Wh, int j, int kb,
                                        int w, int lane, ush* Ws)
{
    #pragma unroll
    for (int c8 = 0; c8 < 4; c8++) {
        int s = (c8 * 4 + w) * 64 + lane;
        int r = s >> 4, scc = (s & 15) ^ (r & 7);
        gload16(Wh + ((size_t)((r >> 4) * 1024 + j * 16 + (r & 15))) * 1024 + kb + scc * 8,
                Ws + (size_t)(c8 * 4 + w) * 512);
    }
}

__device__ __forceinline__ void compute4(int w, int lane, const ush* As,
                                         const ush* Ws, f32x4 acc[4])
{
    #pragma unroll
    for (int kw = 0; kw < 4; kw++) {
        int colo = kw * 32 + (lane >> 4) * 8;
        int ar = w * 16 + (lane & 15);
        f16x8 af = *(const f16x8*)&As[(ar * 128 + colo) ^ ((ar & 7) << 3)];
        #pragma unroll
        for (int g = 0; g < 4; g++) {
            int br = g * 16 + (lane & 15);
            f16x8 bfv = *(const f16x8*)&Ws[(br * 128 + colo) ^ ((br & 7) << 3)];
            acc[g] = __builtin_amdgcn_mfma_f32_16x16x32_f16(af, bfv, acc[g], 0, 0, 0);
        }
    }
}

template <int ISENC>
__device__ __forceinline__ void lstm_step(
    int j, int w, int lane, ush (*Whs)[8192], ush (*As2)[8192],
    const ush* __restrict__ hsrc, ush* __restrict__ hdst,
    const ush* __restrict__ Gx,
    const float* __restrict__ bi, const float* __restrict__ bfg,
    const float* __restrict__ bo, const float* __restrict__ bc,
    float* __restrict__ c, ush* __restrict__ enc_slot)
{
    f32x4 acc[4] = {};
    uint4 ra[4];
    __syncthreads();
    loadA(hsrc, 0, w, lane, ra);
    writeA(As2[0], w, lane, ra);
    loadA(hsrc, 128, w, lane, ra);
    for (int k = 0; k < 8; k++) {
        __syncthreads();                  // drains DMA (weights) + ds_writes
        if (k + 1 < 8) writeA(As2[(k + 1) & 1], w, lane, ra);
        if (k + 2 < 8) loadA(hsrc, (k + 2) * 128, w, lane, ra);
        compute4(w, lane, As2[k & 1], Whs[k], acc);
    }

    const int cc = j * 16 + (lane & 15);
    const float Bi = bi[cc], Bf = bfg[cc], Bo = bo[cc], Bc = bc[cc];
    #pragma unroll
    for (int r = 0; r < 4; r++) {
        int row = w * 16 + (lane >> 4) * 4 + r;
        const ush* gx = Gx + (size_t)row * 4096;
        float zi = acc[0][r] + Bi + h2f(gx[cc]);
        float zf = acc[1][r] + Bf + h2f(gx[1024 + cc]);
        float zo = acc[2][r] + Bo + h2f(gx[2048 + cc]);
        float zc = acc[3][r] + Bc + h2f(gx[3072 + cc]);
        float F = sigm(zf), I = sigm(zi), O = sigm(zo), G = tanhf(zc);
        size_t ci = (size_t)row * 1024 + cc;
        float cn = F * c[ci] + I * G;
        c[ci] = cn;
        float hn = O * tanhf(cn);
        ush hh = f2h(hn);
        hdst[(size_t)row * 2048 + cc] = hh;
        if (ISENC) enc_slot[ci] = hh;
    }
}

__global__ __launch_bounds__(256, 1) void recurrent_all(RecArgs a)
{
    cg::grid_group grid = cg::this_grid();
    __shared__ ush Whs[8][8192];   // 128 KiB resident weight slice
    __shared__ ush As2[2][8192];   // 32 KiB A double-buffer
    const int j = blockIdx.x;
    const int tid = threadIdx.x;
    const int w = tid >> 6, lane = tid & 63;
    ush* comb[2] = {a.comb0, a.comb1};

    // encoder weights -> LDS (drained by first step's inner barrier)
    for (int ch = 0; ch < 8; ch++) stageWh(a.Whe, j, ch * 128, w, lane, Whs[ch]);
    for (int t = 0; t < TXX; t++) {
        lstm_step<1>(j, w, lane, Whs, As2, comb[t & 1], comb[(t + 1) & 1],
                     a.Gxe + (size_t)t * 262144, a.ebi, a.ebf, a.ebo, a.ebc,
                     a.c, a.enc16 + (size_t)t * 65536);
        grid.sync();
    }
    // decoder weights -> LDS (safe: all Whs reads finished before last sync)
    for (int ch = 0; ch < 8; ch++) stageWh(a.Whd, j, ch * 128, w, lane, Whs[ch]);
    for (int s = 0; s < NSS; s++) {
        const ush* hsrc = (s == 0) ? comb[0] : a.Hcat + (size_t)(s - 1) * 131072;
        ush* hdst = a.Hcat + (size_t)s * 131072;
        lstm_step<0>(j, w, lane, Whs, As2, hsrc, hdst,
                     a.Gxd + (size_t)s * 262144, a.dbi, a.dbf, a.dbo, a.dbc,
                     a.c, nullptr);
        grid.sync();
    }
}

// ---------------------------------------------------------------------------
// Batched attention: one block per (s, b). Reads q row, enc16 slice of b,
// writes ctx (f16) into Hcat[row][1024..2047]. Fully parallel (3008 blocks).
// ---------------------------------------------------------------------------
__global__ __launch_bounds__(256) void attn_batched(
    const float* __restrict__ q, const ush* __restrict__ enc16,
    ush* __restrict__ Hcat)
{
    int s = blockIdx.x, b = blockIdx.y;
    int row = s * 64 + b;
    int tid = threadIdx.x;
    __shared__ float qs[1024];
    __shared__ float sc[130];

    for (int i = tid; i < 1024; i += 256) qs[i] = q[(size_t)row * 1024 + i];
    __syncthreads();

    int wave = tid >> 6, lane = tid & 63;
    for (int i = 0; i < 32; i++) {
        int t = wave * 32 + i;
        const ush* e = enc16 + ((size_t)t * 64 + b) * 1024;
        float sv = 0.f;
        #pragma unroll
        for (int jj = 0; jj < 16; jj++) sv += qs[lane + jj * 64] * h2f(e[lane + jj * 64]);
        #pragma unroll
        for (int o = 32; o > 0; o >>= 1) sv += __shfl_down(sv, o, 64);
        if (lane == 0) sc[t] = sv;
    }
    __syncthreads();

    if (wave == 0) {
        float v = fmaxf(sc[lane], sc[lane + 64]);
        #pragma unroll
        for (int o = 32; o > 0; o >>= 1) v = fmaxf(v, __shfl_down(v, o, 64));
        if (lane == 0) sc[128] = v;
    }
    __syncthreads();
    float mx = sc[128];
    if (wave == 0) {
        float e0 = expf(sc[lane] - mx), e1 = expf(sc[lane + 64] - mx);
        sc[lane] = e0; sc[lane + 64] = e1;
        float v = e0 + e1;
        #pragma unroll
        for (int o = 32; o > 0; o >>= 1) v += __shfl_down(v, o, 64);
        if (lane == 0) sc[129] = v;
    }
    __syncthreads();
    float inv = 1.f / sc[129];

    int h0 = tid * 4;
    float a0 = 0.f, a1 = 0.f, a2 = 0.f, a3 = 0.f;
    #pragma unroll 4
    for (int t = 0; t < 128; t++) {
        float av = sc[t] * inv;
        ushx4 ev = *reinterpret_cast<const ushx4*>(
            enc16 + ((size_t)t * 64 + b) * 1024 + h0);
        a0 += av * h2f(ev[0]); a1 += av * h2f(ev[1]);
        a2 += av * h2f(ev[2]); a3 += av * h2f(ev[3]);
    }
    ushx4 o = {f2h(a0), f2h(a1), f2h(a2), f2h(a3)};
    *reinterpret_cast<ushx4*>(&Hcat[(size_t)row * 2048 + 1024 + h0]) = o;
}

// ---------------------------------------------------------------------------
extern "C" void kernel_launch(void* const* d_in, const int* in_sizes, int n_in,
                              void* d_out, int out_size, void* d_ws, size_t ws_size,
                              hipStream_t stream)
{
    const int*   x       = (const int*)d_in[0];
    const int*   y       = (const int*)d_in[1];
    const float* enc_emb = (const float*)d_in[2];
    const float* dec_emb = (const float*)d_in[3];
    const float* encW[4] = {(const float*)d_in[4], (const float*)d_in[6],
                            (const float*)d_in[8], (const float*)d_in[10]};
    const float* encB[4] = {(const float*)d_in[5], (const float*)d_in[7],
                            (const float*)d_in[9], (const float*)d_in[11]};
    const float* decW[4] = {(const float*)d_in[12], (const float*)d_in[14],
                            (const float*)d_in[16], (const float*)d_in[18]};
    const float* decB[4] = {(const float*)d_in[13], (const float*)d_in[15],
                            (const float*)d_in[17], (const float*)d_in[19]};
    const float* attn_w  = (const float*)d_in[20];
    const float* attn_b  = (const float*)d_in[21];
    const float* lin_w   = (const float*)d_in[22];
    const float* lin_b   = (const float*)d_in[23];
    const float* out_w   = (const float*)d_in[24];
    const float* out_b   = (const float*)d_in[25];

    // ws layout: identical extents to proven rounds 3-7 (high-water 30408704 f)
    float* ws = (float*)d_ws;
    float* c      = ws;                          // 65536 f
    ush*   comb0  = (ush*)(ws + 65536);          // 64x2048 ush (region 131072 f)
    ush*   comb1  = (ush*)(ws + 196608);         // 64x2048 ush
    ush*   preh   = (ush*)(ws + 393216);         // 3072x1024 ush
    ush*   enc16  = (ush*)(ws + 1966080);        // 128x64x1024 ush
    ush*   Wt     = (ush*)(ws + 6160384);        // 32000x1024 ush
    ush*   Whe    = (ush*)(ws + 22544384);       // 4096x1024 ush
    ush*   Whd    = (ush*)(ws + 24641536);
    ush*   Wxe    = (ush*)(ws + 26738688);       // 4096x512 ush
    ush*   Wxd    = (ush*)(ws + 27787264);
    ush*   attn_t = (ush*)(ws + 28835840);       // 1024x1024 ush
    ush*   lin_t  = (ush*)(ws + 29360128);       // 1024x2048 ush (end 30408704 f)

    // dead-before-outproj scratch in d_out (385 MB; we use ~129 MB)
    ush*   Gx_enc = (ush*)d_out;                     // 8192*4096
    ush*   Gx_dec = Gx_enc + (size_t)8192 * 4096;    // 3072*4096
    ush*   Xe     = Gx_dec + (size_t)3072 * 4096;    // 8192*512
    ush*   Ye     = Xe + (size_t)8192 * 512;         // 3072*512
    ush*   Hcat   = Ye + (size_t)3072 * 512;         // 3072*2048 (47*64 valid + pad)
    float* qbuf   = (float*)(Hcat + (size_t)3072 * 2048);  // 3072*1024 f32

    hipMemsetAsync(c, 0, (size_t)327680 * 4, stream);         // c + comb0/1 regions
    hipMemsetAsync(preh, 0, (size_t)3072 * 1024 * 2, stream); // pad rows zero

    // ---- weight prep ----
    transpose_w<<<dim3(VV / 32, 32), 256, 0, stream>>>(out_w, Wt, VV, HH);
    transpose_w<<<dim3(32, 32), 256, 0, stream>>>(attn_w, attn_t, HH, HH);
    transpose_w<<<dim3(32, 64), 256, 0, stream>>>(lin_w, lin_t, HH, 2048);
    for (int g = 0; g < 4; g++) {
        transpose_w<<<dim3(32, 32), 256, 0, stream>>>(
            encW[g] + (size_t)EE * HH, Whe + (size_t)g * 1024 * 1024, HH, HH);
        transpose_w<<<dim3(32, 32), 256, 0, stream>>>(
            decW[g] + (size_t)EE * HH, Whd + (size_t)g * 1024 * 1024, HH, HH);
        transpose_w<<<dim3(32, 16), 256, 0, stream>>>(
            encW[g], Wxe + (size_t)g * 1024 * 512, HH, EE);
        transpose_w<<<dim3(32, 16), 256, 0, stream>>>(
            decW[g], Wxd + (size_t)g * 1024 * 512, HH, EE);
    }

    // ---- embedding gathers ----
    gather_emb<<<dim3(2048), 256, 0, stream>>>(enc_emb, x, Xe, TXX, TXX);
    gather_emb<<<dim3(768), 256, 0, stream>>>(dec_emb, y, Ye, TYY, NSS);

    // ---- x-side gate precompute ----
    gemm_f16<2><<<dim3(64, 32), 256, 0, stream>>>(
        Xe, EE, Wxe, nullptr, Gx_enc, EE, 4096, 8192);
    gemm_f16<2><<<dim3(24, 32), 256, 0, stream>>>(
        Ye, EE, Wxd, nullptr, Gx_dec, EE, 4096, 3072);

    // ---- persistent recurrent kernel (cooperative; LSTM steps only) ----
    RecArgs ra;
    ra.comb0 = comb0; ra.comb1 = comb1; ra.Hcat = Hcat; ra.c = c;
    ra.Whe = Whe; ra.Whd = Whd; ra.Gxe = Gx_enc; ra.Gxd = Gx_dec;
    ra.ebi = encB[0]; ra.ebf = encB[1]; ra.ebo = encB[2]; ra.ebc = encB[3];
    ra.dbi = decB[0]; ra.dbf = decB[1]; ra.dbo = decB[2]; ra.dbc = decB[3];
    ra.enc16 = enc16;
    void* kargs[] = {&ra};
    hipLaunchCooperativeKernel((void*)recurrent_all, dim3(64), dim3(256),
                               kargs, 0, stream);

    // ---- post-recurrent batched phases (all wide & parallel) ----
    // q = Hdec @ attn_w^T + attn_b   (M=3008, K=1024)
    gemm_f16<0><<<dim3(24, 8), 256, 0, stream>>>(
        Hcat, 2048, attn_t, attn_b, qbuf, HH, HH, 3008);
    // attention: ctx into Hcat cols 1024..2047
    attn_batched<<<dim3(NSS, 64), 256, 0, stream>>>(qbuf, enc16, Hcat);
    // prelogits = tanh([h|ctx] @ lin_w^T + lin_b)  (M=3008, K=2048)
    gemm_f16<3><<<dim3(24, 8), 256, 0, stream>>>(
        Hcat, 2048, lin_t, lin_b, preh, 2048, HH, 3008);

    // ---- output projection ----
    gemm_f16<1><<<dim3(24, VV / 128), 256, 0, stream>>>(
        preh, HH, Wt, out_b, d_out, HH, VV, 3008);
}

// Round 9
// 1611.966 us; speedup vs baseline: 7.0146x; 3.1992x over previous
//
#include <hip/hip_runtime.h>
#include <hip/hip_bf16.h>
#include <cstddef>

#define BB 64
#define TXX 128
#define TYY 48
#define NSS 47
#define EE 512
#define HH 1024
#define VV 32000

typedef _Float16 f16x8 __attribute__((ext_vector_type(8)));
typedef float f32x4 __attribute__((ext_vector_type(4)));
typedef unsigned short ush;
typedef ush ushx4 __attribute__((ext_vector_type(4)));

__device__ __forceinline__ ush f2h(float x) {
    _Float16 h = (_Float16)x;
    return __builtin_bit_cast(ush, h);
}
__device__ __forceinline__ float h2f(ush u) {
    return (float)__builtin_bit_cast(_Float16, u);
}
// cached global->LDS DMA (proven rounds 1-8)
__device__ __forceinline__ void gload16(const void* g, void* l) {
    __builtin_amdgcn_global_load_lds(
        (const __attribute__((address_space(1))) unsigned int*)g,
        (__attribute__((address_space(3))) unsigned int*)l, 16, 0, 0);
}
__device__ __forceinline__ void st_agent_u32(void* p, unsigned v) {
    __hip_atomic_store((unsigned*)p, v, __ATOMIC_RELAXED, __HIP_MEMORY_SCOPE_AGENT);
}
__device__ __forceinline__ float sigm(float x) { return 1.f / (1.f + expf(-x)); }

// Relaxed row-group barrier (round-7-proven): no cache maintenance.
// vmcnt(0) orders the coherent h-stores before the arrive.
__device__ __forceinline__ void gbar(unsigned* bar, unsigned target) {
    asm volatile("s_waitcnt vmcnt(0)" ::: "memory");
    __syncthreads();
    if (threadIdx.x == 0) {
        __hip_atomic_fetch_add(bar, 1u, __ATOMIC_RELAXED, __HIP_MEMORY_SCOPE_AGENT);
        while (__hip_atomic_load(bar, __ATOMIC_RELAXED, __HIP_MEMORY_SCOPE_AGENT) < target) {
            __builtin_amdgcn_s_sleep(2);
        }
    }
    __syncthreads();
}

// ---------------------------------------------------------------------------
// Transpose + f32->f16 (unchanged)
// ---------------------------------------------------------------------------
__global__ __launch_bounds__(256) void transpose_w(
    const float* __restrict__ W, ush* __restrict__ Wt, int ldW, int ldT)
{
    __shared__ float t[32][33];
    int v0 = blockIdx.x * 32, k0 = blockIdx.y * 32;
    int tv = threadIdx.x & 31, tk = threadIdx.x >> 5;
    #pragma unroll
    for (int i = 0; i < 4; i++) {
        int k = tk * 4 + i;
        t[k][tv] = W[(size_t)(k0 + k) * ldW + v0 + tv];
    }
    __syncthreads();
    #pragma unroll
    for (int i = 0; i < 4; i++) {
        int v = tk * 4 + i;
        Wt[(size_t)(v0 + v) * ldT + k0 + tv] = f2h(t[tv][v]);
    }
}

// ---------------------------------------------------------------------------
// Embedding gather + f16 convert (unchanged)
// ---------------------------------------------------------------------------
__global__ __launch_bounds__(256) void gather_emb(
    const float* __restrict__ emb, const int* __restrict__ tok,
    ush* __restrict__ out, int tokld, int tmax)
{
    int i = blockIdx.x * 256 + threadIdx.x;
    int r = i >> 6, kq = (i & 63) * 8;
    int t = r >> 6, b = r & 63;
    ush v[8];
    if (t < tmax) {
        int tk = tok[b * tokld + t];
        const float* e = emb + (size_t)tk * EE + kq;
        #pragma unroll
        for (int j = 0; j < 8; j++) v[j] = f2h(e[j]);
    } else {
        #pragma unroll
        for (int j = 0; j < 8; j++) v[j] = 0;
    }
    *reinterpret_cast<f16x8*>(&out[(size_t)r * EE + kq]) =
        *reinterpret_cast<f16x8*>(v);
}

// ---------------------------------------------------------------------------
// f16 MFMA GEMM, 128x128 tile (proven). MODE:
//  0: f32 C row-major + bias; 1: out-proj permute + bias; 2: f16 C;
//  3: f16 C, tanh(acc+bias). Guards row<Mvalid (MODE 1: row<3008).
// ---------------------------------------------------------------------------
template <int MODE>
__global__ __launch_bounds__(256) void gemm_f16(
    const ush* __restrict__ A, int lda, const ush* __restrict__ Bt,
    const float* __restrict__ bias, void* __restrict__ Cv,
    int K, int Nld, int Mvalid)
{
    __shared__ ush As[128 * 64];
    __shared__ ush Bs[128 * 64];
    const int tid = threadIdx.x;
    const int lane = tid & 63;
    const int w = tid >> 6;
    const int wm = w >> 1, wn = w & 1;
    const int m0 = blockIdx.x * 128;
    const int n0 = blockIdx.y * 128;

    f32x4 acc[4][4] = {};
    const int srow = w * 32 + (lane >> 3);
    const int skoff = (lane & 7) * 8;

    for (int kb = 0; kb < K; kb += 64) {
        #pragma unroll
        for (int c = 0; c < 4; c++) {
            const ush* ga = A + (size_t)(m0 + srow + c * 8) * lda + kb + skoff;
            gload16(ga, &As[(w * 4 + c) * 512]);
        }
        #pragma unroll
        for (int c = 0; c < 4; c++) {
            const ush* gb = Bt + (size_t)(n0 + srow + c * 8) * K + kb + skoff;
            gload16(gb, &Bs[(w * 4 + c) * 512]);
        }
        __syncthreads();

        #pragma unroll
        for (int kw = 0; kw < 2; kw++) {
            const int koff = kw * 32 + (lane >> 4) * 8;
            f16x8 af[4], bf[4];
            #pragma unroll
            for (int m = 0; m < 4; m++)
                af[m] = *(const f16x8*)&As[(wm * 64 + m * 16 + (lane & 15)) * 64 + koff];
            #pragma unroll
            for (int n = 0; n < 4; n++)
                bf[n] = *(const f16x8*)&Bs[(wn * 64 + n * 16 + (lane & 15)) * 64 + koff];
            #pragma unroll
            for (int m = 0; m < 4; m++)
                #pragma unroll
                for (int n = 0; n < 4; n++)
                    acc[m][n] = __builtin_amdgcn_mfma_f32_16x16x32_f16(
                        af[m], bf[n], acc[m][n], 0, 0, 0);
        }
        __syncthreads();
    }

    #pragma unroll
    for (int n = 0; n < 4; n++) {
        int v = n0 + wn * 64 + n * 16 + (lane & 15);
        float bs = (MODE == 2) ? 0.f : (bias ? bias[v] : 0.f);
        #pragma unroll
        for (int m = 0; m < 4; m++) {
            int rbase = m0 + wm * 64 + m * 16 + (lane >> 4) * 4;
            #pragma unroll
            for (int r = 0; r < 4; r++) {
                int row = rbase + r;
                float val = acc[m][n][r] + bs;
                if (MODE == 1) {
                    if (row < 3008) {
                        int b = row & 63, s = row >> 6;
                        ((float*)Cv)[((size_t)b * NSS + s) * VV + v] = val;
                    }
                } else if (MODE == 0) {
                    if (row < Mvalid) ((float*)Cv)[(size_t)row * Nld + v] = val;
                } else if (MODE == 2) {
                    if (row < Mvalid) ((ush*)Cv)[(size_t)row * Nld + v] = f2h(val);
                } else {
                    if (row < Mvalid)
                        ((ush*)Cv)[(size_t)row * Nld + v] = f2h(tanhf(val));
                }
            }
        }
    }
}

// ===========================================================================
// Persistent recurrent kernel, 2-D decomposition: 256 blocks =
// 4 row-groups (16 batch rows) x 64 col-groups (16 hidden cols x 4 gates).
// Recurrence is per-batch-row independent => only 64-block row-group
// barriers (relaxed counter, no cache maintenance). Weights LDS-resident
// (128 KiB); A-tile 32 KiB; c state in one register per thread.
// h-exchange: agent-coherent stores -> enc16[t] / Hcat[s] (unique address
// per step => plain cached uint4 reads are fresh, L2-shared per XCD).
// ===========================================================================
struct RecArgs {
    const ush *Whe, *Whd, *Gxe, *Gxd;
    const float *ebi, *ebf, *ebo, *ebc;
    const float *dbi, *dbf, *dbo, *dbc;
    ush *enc16, *Hcat;
    unsigned* bar;
};

// Wh chunk (128 k): 64 weight-rows (4 gates x 16 cols of block j)
__device__ __forceinline__ void stageWh(const ush* __restrict__ Wh, int j, int kb,
                                        int w, int lane, ush* Ws)
{
    #pragma unroll
    for (int c8 = 0; c8 < 4; c8++) {
        int s = (c8 * 4 + w) * 64 + lane;
        int r = s >> 4, scc = (s & 15) ^ (r & 7);
        gload16(Wh + ((size_t)((r >> 4) * 1024 + j * 16 + (r & 15))) * 1024 + kb + scc * 8,
                Ws + (size_t)(c8 * 4 + w) * 512);
    }
}

__device__ __forceinline__ void lstm_step2(
    const ush* __restrict__ hsrc, int hstride, ush* __restrict__ hdst, int dstride,
    const ush* __restrict__ gx,
    float Bi, float Bf, float Bo, float Bc, float& creg,
    ush (*Whs)[8192], ush (*AsL)[2048],
    int rg, int j, int tid, unsigned* bar, unsigned target)
{
    const int w = tid >> 6, lane = tid & 63;
    const int r = tid >> 4, sl = tid & 15;      // (local row, slot/cc)
    const int gb = rg * 16 + r;                 // global batch row
    const int gcc = j * 16 + sl;                // global hidden col

    // Gx prefetch (consumed in epilogue; latency hidden under MFMA)
    const ush* gxr = gx + (size_t)gb * 4096 + gcc;
    ush gxi = gxr[0], gxf = gxr[1024], gxo = gxr[2048], gxc = gxr[3072];

    // A-tile stage: [16 rows][1024] as 8 chunks [16][128], slot-XOR swizzle.
    if (hsrc) {
        uint4 ra[8];
        const ush* rowp = hsrc + (size_t)gb * hstride;
        #pragma unroll
        for (int ch = 0; ch < 8; ch++)
            ra[ch] = *reinterpret_cast<const uint4*>(rowp + ch * 128 + sl * 8);
        #pragma unroll
        for (int ch = 0; ch < 8; ch++)
            *reinterpret_cast<uint4*>(&AsL[ch][r * 128 + (sl ^ (r & 7)) * 8]) = ra[ch];
    } else {
        uint4 z = {0, 0, 0, 0};
        #pragma unroll
        for (int ch = 0; ch < 8; ch++)
            *reinterpret_cast<uint4*>(&AsL[ch][r * 128 + sl * 8]) = z;
    }
    __syncthreads();

    // gate-per-wave MFMA: wave w = gate w, [16 rows]x[16 cc], K=1024
    f32x4 acc = {};
    #pragma unroll
    for (int ch = 0; ch < 8; ch++) {
        #pragma unroll
        for (int kw = 0; kw < 4; kw++) {
            int colo = kw * 32 + (lane >> 4) * 8;
            int ar = lane & 15;
            f16x8 af = *(const f16x8*)&AsL[ch][(ar * 128 + colo) ^ ((ar & 7) << 3)];
            int br = w * 16 + (lane & 15);
            f16x8 bfv = *(const f16x8*)&Whs[ch][(br * 128 + colo) ^ ((br & 7) << 3)];
            acc = __builtin_amdgcn_mfma_f32_16x16x32_f16(af, bfv, acc, 0, 0, 0);
        }
    }
    __syncthreads();                 // all waves done reading AsL
    float* zb = (float*)AsL;         // 4 KB z-exchange aliases A-tile
    #pragma unroll
    for (int rr = 0; rr < 4; rr++)
        zb[(w * 16 + (lane >> 4) * 4 + rr) * 16 + (lane & 15)] = acc[rr];
    __syncthreads();

    // elementwise epilogue: thread owns (gb, gcc); c in register
    float zi = zb[(r) * 16 + sl]      + Bi + h2f(gxi);
    float zf = zb[(16 + r) * 16 + sl] + Bf + h2f(gxf);
    float zo = zb[(32 + r) * 16 + sl] + Bo + h2f(gxo);
    float zc = zb[(48 + r) * 16 + sl] + Bc + h2f(gxc);
    float F = sigm(zf), I = sigm(zi), O = sigm(zo), G = tanhf(zc);
    creg = F * creg + I * G;
    float hn = O * tanhf(creg);
    unsigned hv = (unsigned)f2h(hn);
    unsigned other = __shfl_xor(hv, 1, 64);   // pair adjacent cc
    if ((lane & 1) == 0)
        st_agent_u32(hdst + (size_t)gb * dstride + gcc, hv | (other << 16));

    gbar(bar, target);
}

__global__ __launch_bounds__(256) void recurrent_all(RecArgs a)
{
    __shared__ ush Whs[8][8192];   // 128 KiB resident weight slice
    __shared__ ush AsL[8][2048];   // 32 KiB A-tile (aliased by z-exchange)
    const int bid = blockIdx.x;
    const int rg = bid >> 6;       // row-group 0..3 (contiguous in dispatch)
    const int j = bid & 63;        // col-group: hidden cols j*16..j*16+15
    const int tid = threadIdx.x;
    const int w = tid >> 6, lane = tid & 63;
    const int gcc = j * 16 + (tid & 15);
    unsigned* bar = a.bar + rg * 64;   // 256 B apart
    unsigned nb = 0;
    float creg = 0.f;

    // ---- encoder ----
    for (int ch = 0; ch < 8; ch++) stageWh(a.Whe, j, ch * 128, w, lane, Whs[ch]);
    {
        float Bi = a.ebi[gcc], Bf = a.ebf[gcc], Bo = a.ebo[gcc], Bc = a.ebc[gcc];
        for (int t = 0; t < TXX; t++) {
            const ush* hsrc = (t == 0) ? nullptr : a.enc16 + (size_t)(t - 1) * 65536;
            lstm_step2(hsrc, 1024, a.enc16 + (size_t)t * 65536, 1024,
                       a.Gxe + (size_t)t * 262144, Bi, Bf, Bo, Bc, creg,
                       Whs, AsL, rg, j, tid, bar, ++nb * 64u);
        }
    }
    // ---- decoder ----
    for (int ch = 0; ch < 8; ch++) stageWh(a.Whd, j, ch * 128, w, lane, Whs[ch]);
    {
        float Bi = a.dbi[gcc], Bf = a.dbf[gcc], Bo = a.dbo[gcc], Bc = a.dbc[gcc];
        for (int s = 0; s < NSS; s++) {
            const ush* hsrc = (s == 0) ? a.enc16 + (size_t)127 * 65536
                                       : a.Hcat + (size_t)(s - 1) * 64 * 2048;
            int hstride = (s == 0) ? 1024 : 2048;
            lstm_step2(hsrc, hstride, a.Hcat + (size_t)s * 64 * 2048, 2048,
                       a.Gxd + (size_t)s * 262144, Bi, Bf, Bo, Bc, creg,
                       Whs, AsL, rg, j, tid, bar, ++nb * 64u);
        }
    }
}

// ---------------------------------------------------------------------------
// Batched attention (unchanged from round 8): one block per (s, b).
// ---------------------------------------------------------------------------
__global__ __launch_bounds__(256) void attn_batched(
    const float* __restrict__ q, const ush* __restrict__ enc16,
    ush* __restrict__ Hcat)
{
    int s = blockIdx.x, b = blockIdx.y;
    int row = s * 64 + b;
    int tid = threadIdx.x;
    __shared__ float qs[1024];
    __shared__ float sc[130];

    for (int i = tid; i < 1024; i += 256) qs[i] = q[(size_t)row * 1024 + i];
    __syncthreads();

    int wave = tid >> 6, lane = tid & 63;
    for (int i = 0; i < 32; i++) {
        int t = wave * 32 + i;
        const ush* e = enc16 + ((size_t)t * 64 + b) * 1024;
        float sv = 0.f;
        #pragma unroll
        for (int jj = 0; jj < 16; jj++) sv += qs[lane + jj * 64] * h2f(e[lane + jj * 64]);
        #pragma unroll
        for (int o = 32; o > 0; o >>= 1) sv += __shfl_down(sv, o, 64);
        if (lane == 0) sc[t] = sv;
    }
    __syncthreads();

    if (wave == 0) {
        float v = fmaxf(sc[lane], sc[lane + 64]);
        #pragma unroll
        for (int o = 32; o > 0; o >>= 1) v = fmaxf(v, __shfl_down(v, o, 64));
        if (lane == 0) sc[128] = v;
    }
    __syncthreads();
    float mx = sc[128];
    if (wave == 0) {
        float e0 = expf(sc[lane] - mx), e1 = expf(sc[lane + 64] - mx);
        sc[lane] = e0; sc[lane + 64] = e1;
        float v = e0 + e1;
        #pragma unroll
        for (int o = 32; o > 0; o >>= 1) v += __shfl_down(v, o, 64);
        if (lane == 0) sc[129] = v;
    }
    __syncthreads();
    float inv = 1.f / sc[129];

    int h0 = tid * 4;
    float a0 = 0.f, a1 = 0.f, a2 = 0.f, a3 = 0.f;
    #pragma unroll 4
    for (int t = 0; t < 128; t++) {
        float av = sc[t] * inv;
        ushx4 ev = *reinterpret_cast<const ushx4*>(
            enc16 + ((size_t)t * 64 + b) * 1024 + h0);
        a0 += av * h2f(ev[0]); a1 += av * h2f(ev[1]);
        a2 += av * h2f(ev[2]); a3 += av * h2f(ev[3]);
    }
    ushx4 o = {f2h(a0), f2h(a1), f2h(a2), f2h(a3)};
    *reinterpret_cast<ushx4*>(&Hcat[(size_t)row * 2048 + 1024 + h0]) = o;
}

// ---------------------------------------------------------------------------
extern "C" void kernel_launch(void* const* d_in, const int* in_sizes, int n_in,
                              void* d_out, int out_size, void* d_ws, size_t ws_size,
                              hipStream_t stream)
{
    const int*   x       = (const int*)d_in[0];
    const int*   y       = (const int*)d_in[1];
    const float* enc_emb = (const float*)d_in[2];
    const float* dec_emb = (const float*)d_in[3];
    const float* encW[4] = {(const float*)d_in[4], (const float*)d_in[6],
                            (const float*)d_in[8], (const float*)d_in[10]};
    const float* encB[4] = {(const float*)d_in[5], (const float*)d_in[7],
                            (const float*)d_in[9], (const float*)d_in[11]};
    const float* decW[4] = {(const float*)d_in[12], (const float*)d_in[14],
                            (const float*)d_in[16], (const float*)d_in[18]};
    const float* decB[4] = {(const float*)d_in[13], (const float*)d_in[15],
                            (const float*)d_in[17], (const float*)d_in[19]};
    const float* attn_w  = (const float*)d_in[20];
    const float* attn_b  = (const float*)d_in[21];
    const float* lin_w   = (const float*)d_in[22];
    const float* lin_b   = (const float*)d_in[23];
    const float* out_w   = (const float*)d_in[24];
    const float* out_b   = (const float*)d_in[25];

    // ws layout: same proven extents (high-water 30408704 f)
    float* ws = (float*)d_ws;
    ush*   preh   = (ush*)(ws + 393216);         // 3072x1024 ush (3008 valid)
    ush*   enc16  = (ush*)(ws + 1966080);        // 128x64x1024 ush
    ush*   Wt     = (ush*)(ws + 6160384);        // 32000x1024 ush
    ush*   Whe    = (ush*)(ws + 22544384);       // 4096x1024 ush
    ush*   Whd    = (ush*)(ws + 24641536);
    ush*   Wxe    = (ush*)(ws + 26738688);       // 4096x512 ush
    ush*   Wxd    = (ush*)(ws + 27787264);
    ush*   attn_t = (ush*)(ws + 28835840);       // 1024x1024 ush
    ush*   lin_t  = (ush*)(ws + 29360128);       // 1024x2048 ush
    // 4 row-group barrier counters in preh PAD rows (zeroed each launch,
    // only read back as discarded guarded A-pad) — round-7-proven location.
    unsigned* bar = (unsigned*)(preh + (size_t)3008 * 1024);

    // dead-before-outproj scratch in d_out
    ush*   Gx_enc = (ush*)d_out;                     // 8192*4096
    ush*   Gx_dec = Gx_enc + (size_t)8192 * 4096;    // 3072*4096
    ush*   Xe     = Gx_dec + (size_t)3072 * 4096;    // 8192*512
    ush*   Ye     = Xe + (size_t)8192 * 512;         // 3072*512
    ush*   Hcat   = Ye + (size_t)3072 * 512;         // 3072*2048
    float* qbuf   = (float*)(Hcat + (size_t)3072 * 2048);  // 3072*1024 f32

    hipMemsetAsync(preh, 0, (size_t)3072 * 1024 * 2, stream); // pad + counters

    // ---- weight prep ----
    transpose_w<<<dim3(VV / 32, 32), 256, 0, stream>>>(out_w, Wt, VV, HH);
    transpose_w<<<dim3(32, 32), 256, 0, stream>>>(attn_w, attn_t, HH, HH);
    transpose_w<<<dim3(32, 64), 256, 0, stream>>>(lin_w, lin_t, HH, 2048);
    for (int g = 0; g < 4; g++) {
        transpose_w<<<dim3(32, 32), 256, 0, stream>>>(
            encW[g] + (size_t)EE * HH, Whe + (size_t)g * 1024 * 1024, HH, HH);
        transpose_w<<<dim3(32, 32), 256, 0, stream>>>(
            decW[g] + (size_t)EE * HH, Whd + (size_t)g * 1024 * 1024, HH, HH);
        transpose_w<<<dim3(32, 16), 256, 0, stream>>>(
            encW[g], Wxe + (size_t)g * 1024 * 512, HH, EE);
        transpose_w<<<dim3(32, 16), 256, 0, stream>>>(
            decW[g], Wxd + (size_t)g * 1024 * 512, HH, EE);
    }

    // ---- embedding gathers ----
    gather_emb<<<dim3(2048), 256, 0, stream>>>(enc_emb, x, Xe, TXX, TXX);
    gather_emb<<<dim3(768), 256, 0, stream>>>(dec_emb, y, Ye, TYY, NSS);

    // ---- x-side gate precompute ----
    gemm_f16<2><<<dim3(64, 32), 256, 0, stream>>>(
        Xe, EE, Wxe, nullptr, Gx_enc, EE, 4096, 8192);
    gemm_f16<2><<<dim3(24, 32), 256, 0, stream>>>(
        Ye, EE, Wxd, nullptr, Gx_dec, EE, 4096, 3072);

    // ---- persistent recurrent kernel (plain launch; 256 blocks, 1/CU) ----
    RecArgs ra;
    ra.Whe = Whe; ra.Whd = Whd; ra.Gxe = Gx_enc; ra.Gxd = Gx_dec;
    ra.ebi = encB[0]; ra.ebf = encB[1]; ra.ebo = encB[2]; ra.ebc = encB[3];
    ra.dbi = decB[0]; ra.dbf = decB[1]; ra.dbo = decB[2]; ra.dbc = decB[3];
    ra.enc16 = enc16; ra.Hcat = Hcat; ra.bar = bar;
    recurrent_all<<<dim3(256), dim3(256), 0, stream>>>(ra);

    // ---- post-recurrent batched phases ----
    gemm_f16<0><<<dim3(24, 8), 256, 0, stream>>>(
        Hcat, 2048, attn_t, attn_b, qbuf, HH, HH, 3008);
    attn_batched<<<dim3(NSS, 64), 256, 0, stream>>>(qbuf, enc16, Hcat);
    gemm_f16<3><<<dim3(24, 8), 256, 0, stream>>>(
        Hcat, 2048, lin_t, lin_b, preh, 2048, HH, 3008);

    // ---- output projection ----
    gemm_f16<1><<<dim3(24, VV / 128), 256, 0, stream>>>(
        preh, HH, Wt, out_b, d_out, HH, VV, 3008);
}